// Round 7
// baseline (212.954 us; speedup 1.0000x reference)
//
#include <hip/hip_runtime.h>

#define NPIX 4096
#define SCALE 0.125f

typedef _Float16 half8 __attribute__((ext_vector_type(8)));
typedef _Float16 half4 __attribute__((ext_vector_type(4)));
typedef float floatx4 __attribute__((ext_vector_type(4)));

// async global->LDS, 16B per lane. lds base must be wave-uniform; data lands
// at base + lane*16 (gfx950 semantics, learn_hip m97/m104).
__device__ __forceinline__ void async16(void* lds, const void* g) {
  __builtin_amdgcn_global_load_lds(
      (const __attribute__((address_space(1))) unsigned int*)(uintptr_t)g,
      (__attribute__((address_space(3))) unsigned int*)(unsigned)(uintptr_t)lds,
      16, 0, 0);
}

// ---------------------------------------------------------------------------
// PREP (one dispatch, role by blockIdx.z):
//   z < 16 : x[b][256][4096] fp32 -> xt[b][4096][256] fp16 transpose
//   z == 16: split w_qkv fp32 -> hi/lo fp16 (768*256 elems over 256 blocks)
// ---------------------------------------------------------------------------
__global__ __launch_bounds__(256) void prep_kernel(const float* __restrict__ x,
                                                   _Float16* __restrict__ xt,
                                                   const float* __restrict__ w_qkv,
                                                   _Float16* __restrict__ wq_hi,
                                                   _Float16* __restrict__ wq_lo) {
  const int tid = threadIdx.x;
  if (blockIdx.z == 16) {
    int base = (blockIdx.x * 4 + blockIdx.y) * 256 + tid;  // 0..65535
#pragma unroll
    for (int r = 0; r < 3; r++) {
      int i = base + r * 65536;  // 3*65536 = 196608 = 768*256
      float v = w_qkv[i];
      _Float16 h = (_Float16)v;
      wq_hi[i] = h;
      wq_lo[i] = (_Float16)(v - (float)h);
    }
    return;
  }
  __shared__ float t[64][65];
  const int n0 = blockIdx.x * 64, c0 = blockIdx.y * 64, b = blockIdx.z;
  const float* xp = x + (long)b * 256 * NPIX;
  const int r = tid >> 4, c4 = (tid & 15) * 4;
#pragma unroll
  for (int p = 0; p < 4; p++) {
    float4 v = *(const float4*)&xp[(long)(c0 + r + p * 16) * NPIX + n0 + c4];
    t[r + p * 16][c4 + 0] = v.x;
    t[r + p * 16][c4 + 1] = v.y;
    t[r + p * 16][c4 + 2] = v.z;
    t[r + p * 16][c4 + 3] = v.w;
  }
  __syncthreads();
  const int n = tid >> 2, cg = (tid & 3) * 16;
  alignas(16) _Float16 o[16];
#pragma unroll
  for (int i = 0; i < 16; i++) o[i] = (_Float16)t[cg + i][n];
  _Float16* dst = &xt[((long)b * NPIX + n0 + n) * 256 + c0 + cg];
  *(float4*)dst = *(float4*)&o[0];
  *(float4*)(dst + 8) = *(float4*)&o[8];
}

// ---------------------------------------------------------------------------
// Shared LDS union for the merged q/kv kernel (max 48 KB; every member
// overlaps, exactly matching each role's original internal union).
// ---------------------------------------------------------------------------
union alignas(16) MU {
  _Float16 q_st[2][3][128 * 32];  // q staging 48 KB (dbuf x {Ah,Al,B})
  _Float16 q_pt[128][128];        // q epilogue P-tile 32 KB
  _Float16 k_st[2][2][128 * 32];  // kv staging 32 KB (dbuf x {A,B})
  _Float16 k_ev[128][136];        // kv epilogue 34.8 KB (exp(k) | v)
};

// ---------------------------------------------------------------------------
// q role: FUSED q-GEMM (split-A) + column softmax over d -> PT fp16.
// Identical to round-6 q_gemm_softmax (passed, absmax 6.1e-5).
// ---------------------------------------------------------------------------
__device__ __forceinline__ void q_body(MU& u, int idx,
                                       const _Float16* __restrict__ Ahp,
                                       const _Float16* __restrict__ Alp,
                                       const _Float16* __restrict__ Bt,
                                       _Float16* __restrict__ PT) {
  const int tid = threadIdx.x;
  const int n0 = (idx & 31) * 128, m0 = ((idx >> 5) & 1) * 128;
  const int bz = idx >> 6;
  const _Float16* Bp = Bt + (long)bz * NPIX * 256;
  const int wv = tid >> 6, l = tid & 63;
  const int r16 = l & 15, q = l >> 4;
  const int mb = (wv >> 1) * 64, nb = (wv & 1) * 64;
  const int r1 = tid >> 2;
  const int o1 = ((tid & 3) * 8) ^ (((r1 >> 1) & 3) * 8);
  const int r2 = r1 + 64;
  const int ldsc1 = (wv * 64) * 8;
  const int ldsc2 = (256 + wv * 64) * 8;
  const int q8 = (q * 8) ^ (((r16 >> 1) & 3) * 8);

  auto STAGE = [&](int buf, int kt) {
    const int k0 = kt * 32;
    async16(&u.q_st[buf][0][ldsc1], &Ahp[(long)(m0 + r1) * 256 + k0 + o1]);
    async16(&u.q_st[buf][0][ldsc2], &Ahp[(long)(m0 + r2) * 256 + k0 + o1]);
    async16(&u.q_st[buf][1][ldsc1], &Alp[(long)(m0 + r1) * 256 + k0 + o1]);
    async16(&u.q_st[buf][1][ldsc2], &Alp[(long)(m0 + r2) * 256 + k0 + o1]);
    async16(&u.q_st[buf][2][ldsc1], &Bp[(long)(n0 + r1) * 256 + k0 + o1]);
    async16(&u.q_st[buf][2][ldsc2], &Bp[(long)(n0 + r2) * 256 + k0 + o1]);
  };

  floatx4 acc[4][4];
#pragma unroll
  for (int i = 0; i < 4; i++)
#pragma unroll
    for (int j = 0; j < 4; j++) acc[i][j] = (floatx4){0.f, 0.f, 0.f, 0.f};

  STAGE(0, 0);
  __syncthreads();
  int cur = 0;
  for (int kt = 0; kt < 8; kt++) {
    if (kt < 7) STAGE(cur ^ 1, kt + 1);
    half8 fa[4], flo[4], fb[4];
#pragma unroll
    for (int i = 0; i < 4; i++) {
      fa[i] = *(const half8*)&u.q_st[cur][0][(mb + i * 16 + r16) * 32 + q8];
      flo[i] = *(const half8*)&u.q_st[cur][1][(mb + i * 16 + r16) * 32 + q8];
      fb[i] = *(const half8*)&u.q_st[cur][2][(nb + i * 16 + r16) * 32 + q8];
    }
#pragma unroll
    for (int i = 0; i < 4; i++)
#pragma unroll
      for (int j = 0; j < 4; j++) {
        acc[i][j] = __builtin_amdgcn_mfma_f32_16x16x32_f16(fa[i], fb[j], acc[i][j], 0, 0, 0);
        acc[i][j] = __builtin_amdgcn_mfma_f32_16x16x32_f16(flo[i], fb[j], acc[i][j], 0, 0, 0);
      }
    __syncthreads();
    cur ^= 1;
  }

  // per-column softmax over d (wave holds one head's 64 rows)
#pragma unroll
  for (int j = 0; j < 4; j++) {
    float s = 0.f;
#pragma unroll
    for (int i = 0; i < 4; i++)
#pragma unroll
      for (int t = 0; t < 4; t++) {
        float e = __expf(acc[i][j][t]);
        acc[i][j][t] = e;
        s += e;
      }
    s += __shfl_xor(s, 16, 64);
    s += __shfl_xor(s, 32, 64);
    const float rinv = 1.0f / s;
    const int nl = nb + j * 16 + r16;
    const int swz = (nl & 7) * 8;
#pragma unroll
    for (int i = 0; i < 4; i++) {
      half4 h4;
#pragma unroll
      for (int t = 0; t < 4; t++) h4[t] = (_Float16)(acc[i][j][t] * rinv);
      *(half4*)&u.q_pt[nl][(mb + i * 16 + q * 4) ^ swz] = h4;
    }
  }
  __syncthreads();
  const int rbase = tid >> 4, c16 = tid & 15;
  _Float16* dst = PT + ((long)(bz * 2 + (m0 >> 7)) * NPIX + n0) * 128;
#pragma unroll
  for (int k = 0; k < 8; k++) {
    const int row = rbase + k * 16;
    const int chunk = c16 ^ (row & 7);
    float4 v = *(const float4*)&u.q_pt[row][chunk * 8];
    *(float4*)&dst[(long)row * 128 + c16 * 8] = v;
  }
}

// ---------------------------------------------------------------------------
// kv role: FUSED k/v GEMM (single-fp16 A) + exp(k)@v^T context partials.
// Identical to round-6 kv_ctx_gemm (passed, absmax 6.1e-5). CPB=2.
// ---------------------------------------------------------------------------
__device__ __forceinline__ void kv_body(MU& u, int idx,
                                        const _Float16* __restrict__ Ahp,
                                        const _Float16* __restrict__ Bt,
                                        float* __restrict__ pbuf,
                                        float* __restrict__ rsbuf) {
  const int tid = threadIdx.x;
  const int cg = idx & 15;         // chunk-group (2 chunks of 128)
  const int hi = (idx >> 4) & 3;   // head
  const int b = idx >> 6;          // batch
  const _Float16* Bp = Bt + (long)b * NPIX * 256;
  const int wv = tid >> 6, l = tid & 63;
  const int r16 = l & 15, q = l >> 4;
  const int mb = (wv >> 1) * 64, nb = (wv & 1) * 64;
  const int r1 = tid >> 2;
  const int o1 = ((tid & 3) * 8) ^ (((r1 >> 1) & 3) * 8);
  const int ldsc1 = (wv * 64) * 8;
  const int ldsc2 = (256 + wv * 64) * 8;
  const int q8 = (q * 8) ^ (((r16 >> 1) & 3) * 8);
  const long gAk = (long)(256 + hi * 64 + r1) * 256;
  const long gAv = (long)(512 + hi * 64 + r1) * 256;

  auto STAGE = [&](int buf, int kt, int n0) {
    const int k0 = kt * 32;
    async16(&u.k_st[buf][0][ldsc1], &Ahp[gAk + k0 + o1]);
    async16(&u.k_st[buf][0][ldsc2], &Ahp[gAv + k0 + o1]);
    async16(&u.k_st[buf][1][ldsc1], &Bp[(long)(n0 + r1) * 256 + k0 + o1]);
    async16(&u.k_st[buf][1][ldsc2], &Bp[(long)(n0 + 64 + r1) * 256 + k0 + o1]);
  };

  floatx4 c2[4];
#pragma unroll
  for (int j = 0; j < 4; j++) c2[j] = (floatx4){0.f, 0.f, 0.f, 0.f};
  float rs = 0.f;

  for (int cs = 0; cs < 2; cs++) {
    const int n0 = (cg * 2 + cs) * 128;
    floatx4 acc[4][4];
#pragma unroll
    for (int i = 0; i < 4; i++)
#pragma unroll
      for (int j = 0; j < 4; j++) acc[i][j] = (floatx4){0.f, 0.f, 0.f, 0.f};

    STAGE(0, 0, n0);
    __syncthreads();
    int cur = 0;
    for (int kt = 0; kt < 8; kt++) {
      if (kt < 7) STAGE(cur ^ 1, kt + 1, n0);
      half8 fa[4], fb[4];
#pragma unroll
      for (int i = 0; i < 4; i++) {
        fa[i] = *(const half8*)&u.k_st[cur][0][(mb + i * 16 + r16) * 32 + q8];
        fb[i] = *(const half8*)&u.k_st[cur][1][(nb + i * 16 + r16) * 32 + q8];
      }
#pragma unroll
      for (int i = 0; i < 4; i++)
#pragma unroll
        for (int j = 0; j < 4; j++)
          acc[i][j] = __builtin_amdgcn_mfma_f32_16x16x32_f16(fa[i], fb[j], acc[i][j], 0, 0, 0);
      __syncthreads();
      cur ^= 1;
    }

    // epilogue: acc -> exp(k)/v fp16 tile in LDS (stride 136)
    const bool is_k = (mb == 0);
#pragma unroll
    for (int i = 0; i < 4; i++) {
      const int row = mb + i * 16 + q * 4;
#pragma unroll
      for (int j = 0; j < 4; j++) {
        const int col = nb + j * 16 + r16;
#pragma unroll
        for (int t = 0; t < 4; t++) {
          const float vv0 = acc[i][j][t];
          u.k_ev[row + t][col] = (_Float16)(is_k ? __expf(vv0) : vv0);
        }
      }
    }
    __syncthreads();

    // context partial: c2[d][e] += sum_n exp(k[d][n]) v[e][n], K=128
#pragma unroll
    for (int ks = 0; ks < 4; ks++) {
      half8 a = *(const half8*)&u.k_ev[wv * 16 + r16][ks * 32 + q * 8];
#pragma unroll
      for (int ii = 0; ii < 8; ii++) rs += (float)a[ii];
#pragma unroll
      for (int j = 0; j < 4; j++) {
        half8 bv = *(const half8*)&u.k_ev[64 + j * 16 + r16][ks * 32 + q * 8];
        c2[j] = __builtin_amdgcn_mfma_f32_16x16x32_f16(a, bv, c2[j], 0, 0, 0);
      }
    }
    __syncthreads();  // ev reads done before next chunk's STAGE overwrites
  }

  rs += __shfl_xor(rs, 16, 64);
  rs += __shfl_xor(rs, 32, 64);
  const int bh = b * 4 + hi;
  float* pp = pbuf + ((long)bh * 16 + cg) * 4096;
#pragma unroll
  for (int j = 0; j < 4; j++)
#pragma unroll
    for (int reg = 0; reg < 4; reg++)
      pp[(wv * 16 + q * 4 + reg) * 64 + j * 16 + r16] = c2[j][reg];
  if (l < 16) rsbuf[((long)bh * 16 + cg) * 64 + wv * 16 + r16] = rs;
}

// ---------------------------------------------------------------------------
// MERGED q + kv dispatch: roles interleaved by blockIdx.x&1 so every CU gets
// a mix of heterogeneous blocks (q MFMA overlaps kv staging and vice versa --
// the m114 co-schedule effect; round-5 showed homogeneous extra blocks don't
// help the lockstep 2-phase structure, heterogeneous ones can).
// ---------------------------------------------------------------------------
__global__ __launch_bounds__(256) void qkv_mega(const _Float16* __restrict__ wq_hi,
                                                const _Float16* __restrict__ wq_lo,
                                                const _Float16* __restrict__ xt,
                                                _Float16* __restrict__ PT,
                                                float* __restrict__ pbuf,
                                                float* __restrict__ rsbuf) {
  __shared__ MU u;
  const int idx = blockIdx.x >> 1;
  if ((blockIdx.x & 1) == 0)
    q_body(u, idx, wq_hi, wq_lo, xt, PT);
  else
    kv_body(u, idx, wq_hi, xt, pbuf, rsbuf);
}

// ---------------------------------------------------------------------------
// FUSED reduce_ctx + zinv + mctx:
//   ctx[d][e] = sum_16 pbuf partials; kinvz[d] = 1/sum_16 rsbuf
//   M_b[c][h*64+d] = SCALE * kinvz[d] * sum_e w_out[c][h*64+e] * ctx[d][e]
// ---------------------------------------------------------------------------
__global__ __launch_bounds__(256) void mctx_fused(const float* __restrict__ w_out,
                                                  const float* __restrict__ pbuf,
                                                  const float* __restrict__ rsbuf,
                                                  _Float16* __restrict__ Mhi,
                                                  _Float16* __restrict__ Mlo) {
  __shared__ float sctxT[64][65];  // [e][d], +1 pad
  __shared__ float sinv[64];
  const int cq = blockIdx.x, h = blockIdx.y, b = blockIdx.z;
  const int bh = b * 4 + h;
  const float* pp = pbuf + (long)bh * 16 * 4096;  // 16 partials of [d][e]
  const int tid = threadIdx.x;
  {
    const int d = tid >> 2, e0 = (tid & 3) * 16;
    float s0[16];
#pragma unroll
    for (int i = 0; i < 16; i++) s0[i] = 0.f;
    for (int c = 0; c < 16; c++) {
#pragma unroll
      for (int k = 0; k < 4; k++) {
        float4 v = *(const float4*)&pp[(long)c * 4096 + d * 64 + e0 + k * 4];
        s0[k * 4 + 0] += v.x;
        s0[k * 4 + 1] += v.y;
        s0[k * 4 + 2] += v.z;
        s0[k * 4 + 3] += v.w;
      }
    }
#pragma unroll
    for (int i = 0; i < 16; i++) sctxT[e0 + i][d] = s0[i];
  }
  if (tid < 64) {
    const float* rp = rsbuf + (long)bh * 16 * 64 + tid;
    float z = 0.f;
#pragma unroll
    for (int c = 0; c < 16; c++) z += rp[c * 64];
    sinv[tid] = 1.0f / z;
  }
  __syncthreads();
  const int c = cq * 64 + (tid >> 2);
  const int d0 = (tid & 3) * 16;
  const float* wp = w_out + (long)c * 256 + h * 64;
  float acc[16];
#pragma unroll
  for (int i = 0; i < 16; i++) acc[i] = 0.f;
#pragma unroll
  for (int e4 = 0; e4 < 16; e4++) {
    float4 wv = *(const float4*)&wp[e4 * 4];
#pragma unroll
    for (int u2 = 0; u2 < 4; u2++) {
      const float we = ((const float*)&wv)[u2];
      const int e = e4 * 4 + u2;
#pragma unroll
      for (int dd = 0; dd < 16; dd++) acc[dd] = fmaf(we, sctxT[e][d0 + dd], acc[dd]);
    }
  }
  alignas(16) _Float16 hi16[16], lo16[16];
#pragma unroll
  for (int k4 = 0; k4 < 4; k4++) {
    float4 zv = *(const float4*)&sinv[d0 + k4 * 4];
#pragma unroll
    for (int u2 = 0; u2 < 4; u2++) {
      const int dd = k4 * 4 + u2;
      float v = acc[dd] * (SCALE * ((const float*)&zv)[u2]);
      _Float16 hh = (_Float16)v;
      hi16[dd] = hh;
      lo16[dd] = (_Float16)(v - (float)hh);
    }
  }
  _Float16* mh = Mhi + ((long)b * 256 + c) * 256 + h * 64 + d0;
  _Float16* ml = Mlo + ((long)b * 256 + c) * 256 + h * 64 + d0;
#pragma unroll
  for (int k = 0; k < 2; k++) {
    *(float4*)&mh[k * 8] = *(float4*)&hi16[k * 8];
    *(float4*)&ml[k * 8] = *(float4*)&lo16[k * 8];
  }
}

// ---------------------------------------------------------------------------
// final GEMM: out[b][256][4096] = (Mhi+Mlo)[b] @ PT[b]^T + b_out
// B layout: PT[b][s][4096][128], s = K-half (kt>>2). 2-phase prefetch.
// ---------------------------------------------------------------------------
__global__ __launch_bounds__(256) void out_gemm(const _Float16* __restrict__ Mhi,
                                                const _Float16* __restrict__ Mlo,
                                                const _Float16* __restrict__ PT,
                                                float* __restrict__ C,
                                                const float* __restrict__ bias) {
  __shared__ _Float16 st[2][3][128 * 32];  // 48 KB dbuf staging
  const int tid = threadIdx.x;
  const int n0 = blockIdx.x * 128, m0 = blockIdx.y * 128;
  const int b = blockIdx.z;
  const _Float16* Ah = Mhi + (long)b * 65536;
  const _Float16* Al = Mlo + (long)b * 65536;
  float* Cp = C + (long)b * 256 * NPIX;
  const int wv = tid >> 6, l = tid & 63;
  const int r16 = l & 15, q = l >> 4;
  const int mb = (wv >> 1) * 64, nb = (wv & 1) * 64;
  const int r1 = tid >> 2;
  const int o1 = ((tid & 3) * 8) ^ (((r1 >> 1) & 3) * 8);
  const int r2 = r1 + 64;
  const int ldsc1 = (wv * 64) * 8;
  const int ldsc2 = (256 + wv * 64) * 8;
  const int q8 = (q * 8) ^ (((r16 >> 1) & 3) * 8);

  auto STAGE = [&](int buf, int kt) {
    const int k0 = kt * 32;
    async16(&st[buf][0][ldsc1], &Ah[(long)(m0 + r1) * 256 + k0 + o1]);
    async16(&st[buf][0][ldsc2], &Ah[(long)(m0 + r2) * 256 + k0 + o1]);
    async16(&st[buf][1][ldsc1], &Al[(long)(m0 + r1) * 256 + k0 + o1]);
    async16(&st[buf][1][ldsc2], &Al[(long)(m0 + r2) * 256 + k0 + o1]);
    const _Float16* Bk = PT + ((long)(b * 2 + (kt >> 2)) * NPIX + n0) * 128;
    async16(&st[buf][2][ldsc1], &Bk[(long)r1 * 128 + (kt & 3) * 32 + o1]);
    async16(&st[buf][2][ldsc2], &Bk[(long)(r1 + 64) * 128 + (kt & 3) * 32 + o1]);
  };

  floatx4 acc[4][4];
#pragma unroll
  for (int i = 0; i < 4; i++)
#pragma unroll
    for (int j = 0; j < 4; j++) acc[i][j] = (floatx4){0.f, 0.f, 0.f, 0.f};

  STAGE(0, 0);
  __syncthreads();
  int cur = 0;
  for (int kt = 0; kt < 8; kt++) {
    if (kt < 7) STAGE(cur ^ 1, kt + 1);
    half8 fa[4], flo[4], fb[4];
#pragma unroll
    for (int i = 0; i < 4; i++) {
      fa[i] = *(const half8*)&st[cur][0][(mb + i * 16 + r16) * 32 + q8];
      flo[i] = *(const half8*)&st[cur][1][(mb + i * 16 + r16) * 32 + q8];
      fb[i] = *(const half8*)&st[cur][2][(nb + i * 16 + r16) * 32 + q8];
    }
#pragma unroll
    for (int i = 0; i < 4; i++)
#pragma unroll
      for (int j = 0; j < 4; j++) {
        acc[i][j] = __builtin_amdgcn_mfma_f32_16x16x32_f16(fa[i], fb[j], acc[i][j], 0, 0, 0);
        acc[i][j] = __builtin_amdgcn_mfma_f32_16x16x32_f16(flo[i], fb[j], acc[i][j], 0, 0, 0);
      }
    __syncthreads();
    cur ^= 1;
  }
#pragma unroll
  for (int i = 0; i < 4; i++) {
    const int mrow = m0 + mb + i * 16 + q * 4;
#pragma unroll
    for (int t = 0; t < 4; t++) {
      float bz = bias[mrow + t];
#pragma unroll
      for (int j = 0; j < 4; j++) {
        Cp[(long)(mrow + t) * NPIX + n0 + nb + j * 16 + r16] = acc[i][j][t] + bz;
      }
    }
  }
}

extern "C" void kernel_launch(void* const* d_in, const int* in_sizes, int n_in,
                              void* d_out, int out_size, void* d_ws, size_t ws_size,
                              hipStream_t stream) {
  const float* x = (const float*)d_in[0];      // [16][256][4096]
  const float* w_qkv = (const float*)d_in[1];  // [768][256]
  const float* w_out = (const float*)d_in[2];  // [256][256]
  const float* b_out = (const float*)d_in[3];  // [256]
  float* out = (float*)d_out;                  // [16][256][4096]

  // d_ws layout:
  _Float16* PT = (_Float16*)d_ws;                           // [16][2][4096][128] = 32 MB
  float* rsbuf = (float*)(PT + (long)16 * 2 * NPIX * 128);  // 64bh*16p*64 = 256 KB
  _Float16* wq_hi = (_Float16*)(rsbuf + 64 * 16 * 64);
  _Float16* wq_lo = wq_hi + 768 * 256;
  _Float16* Mhi = wq_lo + 768 * 256;                        // 16*256*256 fp16 = 2 MB
  _Float16* Mlo = Mhi + 16 * 256 * 256;                     // 2 MB
  // d_out scratch (dead until out_gemm writes it):
  _Float16* xt = (_Float16*)d_out;                          // [0..32MB)
  float* pbuf = (float*)d_out + (1 << 23);                  // [32MB..48MB): 64bh*16p*4096

  // prep: transpose (z<16) + w_qkv split (z==16), one dispatch
  prep_kernel<<<dim3(64, 4, 17), 256, 0, stream>>>(x, xt, w_qkv, wq_hi, wq_lo);
  // merged q-GEMM+softmax and kv-GEMM+context (interleaved roles)
  qkv_mega<<<2048, 256, 0, stream>>>(wq_hi, wq_lo, xt, PT, pbuf, rsbuf);
  // fused partial-reduce + 1/Z + M_b = w_out @ ctx^T * diag(SCALE*invZ)
  mctx_fused<<<dim3(4, 4, 16), 256, 0, stream>>>(w_out, pbuf, rsbuf, Mhi, Mlo);
  // final = M_b @ P_b + b_out
  out_gemm<<<dim3(32, 2, 16), 256, 0, stream>>>(Mhi, Mlo, PT, out, b_out);
}

// Round 9
// 209.608 us; speedup vs baseline: 1.0160x; 1.0160x over previous
//
#include <hip/hip_runtime.h>

#define NPIX 4096
#define SCALE 0.125f

typedef _Float16 half8 __attribute__((ext_vector_type(8)));
typedef _Float16 half4 __attribute__((ext_vector_type(4)));
typedef float floatx4 __attribute__((ext_vector_type(4)));

// async global->LDS, 16B per lane. lds base must be wave-uniform; data lands
// at base + lane*16 (gfx950 semantics, learn_hip m97/m104).
__device__ __forceinline__ void async16(void* lds, const void* g) {
  __builtin_amdgcn_global_load_lds(
      (const __attribute__((address_space(1))) unsigned int*)(uintptr_t)g,
      (__attribute__((address_space(3))) unsigned int*)(unsigned)(uintptr_t)lds,
      16, 0, 0);
}

// counted vmem wait (T4): n is wave-uniform; literal immediates per branch.
__device__ __forceinline__ void vmwait(int n) {
  if (n >= 6)      asm volatile("s_waitcnt vmcnt(6)" ::: "memory");
  else if (n >= 4) asm volatile("s_waitcnt vmcnt(4)" ::: "memory");
  else             asm volatile("s_waitcnt vmcnt(0)" ::: "memory");
}

// Raced in round 8: raw s_barrier is NOT a compiler memory fence -- hipcc
// hoisted reg-dependent LDS stores / ds_reads across it (guide rule #18).
// sched_barrier(0) on both sides pins the scheduling region boundary.
__device__ __forceinline__ void pipe_barrier(int n) {
  __builtin_amdgcn_sched_barrier(0);
  vmwait(n);
  __builtin_amdgcn_s_barrier();
  __builtin_amdgcn_sched_barrier(0);
}

// ---------------------------------------------------------------------------
// split fp32 -> hi/lo fp16 (a = hi + lo, ~21 mantissa bits kept)
// ---------------------------------------------------------------------------
__global__ __launch_bounds__(256) void split16_kernel(const float* __restrict__ w,
                                                      _Float16* __restrict__ hi,
                                                      _Float16* __restrict__ lo, int n) {
  int i = blockIdx.x * 256 + threadIdx.x;
  if (i < n) {
    float v = w[i];
    _Float16 h = (_Float16)v;
    hi[i] = h;
    lo[i] = (_Float16)(v - (float)h);
  }
}

// ---------------------------------------------------------------------------
// x[b][256][4096] fp32 -> xt[b][4096][256] fp16 (K-contiguous for B-operand)
// ---------------------------------------------------------------------------
__global__ __launch_bounds__(256) void transpose16_kernel(const float* __restrict__ x,
                                                          _Float16* __restrict__ xt) {
  __shared__ float t[64][65];
  const int n0 = blockIdx.x * 64, c0 = blockIdx.y * 64, b = blockIdx.z;
  const float* xp = x + (long)b * 256 * NPIX;
  const int tid = threadIdx.x;
  const int r = tid >> 4, c4 = (tid & 15) * 4;
#pragma unroll
  for (int p = 0; p < 4; p++) {
    float4 v = *(const float4*)&xp[(long)(c0 + r + p * 16) * NPIX + n0 + c4];
    t[r + p * 16][c4 + 0] = v.x;
    t[r + p * 16][c4 + 1] = v.y;
    t[r + p * 16][c4 + 2] = v.z;
    t[r + p * 16][c4 + 3] = v.w;
  }
  __syncthreads();
  const int n = tid >> 2, cg = (tid & 3) * 16;
  alignas(16) _Float16 o[16];
#pragma unroll
  for (int i = 0; i < 16; i++) o[i] = (_Float16)t[cg + i][n];
  _Float16* dst = &xt[((long)b * NPIX + n0 + n) * 256 + c0 + cg];
  *(float4*)dst = *(float4*)&o[0];
  *(float4*)(dst + 8) = *(float4*)&o[8];
}

// ---------------------------------------------------------------------------
// FUSED q-GEMM + column softmax over d. 3-DEEP counted-vmcnt pipeline:
// stage t+2 issued at iter t; bottom wait = vmcnt(6) (stage t+1 complete,
// t+2 in flight) + fenced s_barrier. 72 KB LDS -> 2 blocks/CU.
// ---------------------------------------------------------------------------
__global__ __launch_bounds__(256) void q_gemm_softmax(const _Float16* __restrict__ Ahp,
                                                      const _Float16* __restrict__ Alp,
                                                      const _Float16* __restrict__ Bt,
                                                      _Float16* __restrict__ PT) {
  union alignas(16) QU {
    _Float16 st[3][3][128 * 32];  // [buf][Ah,Al,B] 72 KB 3-deep staging
    _Float16 pt[128][128];        // 32 KB, epilogue P-tile (XOR-swizzled cols)
  };
  __shared__ QU u;
  const int tid = threadIdx.x;
  const int n0 = blockIdx.x * 128, m0 = blockIdx.y * 128;
  const int bz = blockIdx.z;
  const _Float16* Bp = Bt + (long)bz * NPIX * 256;
  const int wv = tid >> 6, l = tid & 63;
  const int r16 = l & 15, q = l >> 4;
  const int mb = (wv >> 1) * 64, nb = (wv & 1) * 64;
  const int r1 = tid >> 2;
  const int o1 = ((tid & 3) * 8) ^ (((r1 >> 1) & 3) * 8);
  const int r2 = r1 + 64;
  const int ldsc1 = (wv * 64) * 8;
  const int ldsc2 = (256 + wv * 64) * 8;
  const int q8 = (q * 8) ^ (((r16 >> 1) & 3) * 8);

  auto STAGE = [&](int buf, int kt) {
    const int k0 = kt * 32;
    async16(&u.st[buf][0][ldsc1], &Ahp[(long)(m0 + r1) * 256 + k0 + o1]);
    async16(&u.st[buf][0][ldsc2], &Ahp[(long)(m0 + r2) * 256 + k0 + o1]);
    async16(&u.st[buf][1][ldsc1], &Alp[(long)(m0 + r1) * 256 + k0 + o1]);
    async16(&u.st[buf][1][ldsc2], &Alp[(long)(m0 + r2) * 256 + k0 + o1]);
    async16(&u.st[buf][2][ldsc1], &Bp[(long)(n0 + r1) * 256 + k0 + o1]);
    async16(&u.st[buf][2][ldsc2], &Bp[(long)(n0 + r2) * 256 + k0 + o1]);
  };

  floatx4 acc[4][4];
#pragma unroll
  for (int i = 0; i < 4; i++)
#pragma unroll
    for (int j = 0; j < 4; j++) acc[i][j] = (floatx4){0.f, 0.f, 0.f, 0.f};

  STAGE(0, 0);
  STAGE(1, 1);
  pipe_barrier(6);  // stage0 landed (stage1 in flight)
  int cc = 0;
  for (int kt = 0; kt < 8; kt++) {
    if (kt < 6) {
      int sb = cc + 2;
      if (sb >= 3) sb -= 3;
      STAGE(sb, kt + 2);
    }
    half8 fa[4], flo[4], fb[4];
#pragma unroll
    for (int i = 0; i < 4; i++) {
      fa[i] = *(const half8*)&u.st[cc][0][(mb + i * 16 + r16) * 32 + q8];
      flo[i] = *(const half8*)&u.st[cc][1][(mb + i * 16 + r16) * 32 + q8];
      fb[i] = *(const half8*)&u.st[cc][2][(nb + i * 16 + r16) * 32 + q8];
    }
#pragma unroll
    for (int i = 0; i < 4; i++)
#pragma unroll
      for (int j = 0; j < 4; j++) {
        acc[i][j] = __builtin_amdgcn_mfma_f32_16x16x32_f16(fa[i], fb[j], acc[i][j], 0, 0, 0);
        acc[i][j] = __builtin_amdgcn_mfma_f32_16x16x32_f16(flo[i], fb[j], acc[i][j], 0, 0, 0);
      }
    pipe_barrier(kt < 6 ? 6 : 0);  // next buf ready; deeper stage in flight
    cc = (cc == 2) ? 0 : cc + 1;
  }

  // ---- epilogue: per-column softmax over d (wave holds one head's 64 rows) ----
  // (vmcnt=0 drained + fenced barrier -> pt overlay safe)
#pragma unroll
  for (int j = 0; j < 4; j++) {
    float s = 0.f;
#pragma unroll
    for (int i = 0; i < 4; i++)
#pragma unroll
      for (int t = 0; t < 4; t++) {
        float e = __expf(acc[i][j][t]);
        acc[i][j][t] = e;
        s += e;
      }
    s += __shfl_xor(s, 16, 64);
    s += __shfl_xor(s, 32, 64);
    const float rinv = 1.0f / s;
    const int nl = nb + j * 16 + r16;
    const int swz = (nl & 7) * 8;  // bank-spread: (q,nl&7) -> 32 distinct banks
#pragma unroll
    for (int i = 0; i < 4; i++) {
      half4 h4;
#pragma unroll
      for (int t = 0; t < 4; t++) h4[t] = (_Float16)(acc[i][j][t] * rinv);
      *(half4*)&u.pt[nl][(mb + i * 16 + q * 4) ^ swz] = h4;
    }
  }
  __syncthreads();
  // ---- dump P-tile: rows contiguous (PT row stride = 128 c), 1KB/wave-instr ----
  const int rbase = tid >> 4, c16 = tid & 15;
  _Float16* dst = PT + ((long)(bz * 2 + (m0 >> 7)) * NPIX + n0) * 128;
#pragma unroll
  for (int k = 0; k < 8; k++) {
    const int row = rbase + k * 16;
    const int chunk = c16 ^ (row & 7);
    float4 v = *(const float4*)&u.pt[row][chunk * 8];
    *(float4*)&dst[(long)row * 128 + c16 * 8] = v;
  }
}

// ---------------------------------------------------------------------------
// FUSED k/v GEMM (single-fp16 A) + exp(k)@v^T context partials. 3-DEEP
// counted-vmcnt pipeline; 3x16KB staging = 48 KB union (3 blocks/CU).
// CPB=2, c2 accumulates across chunks.
// ---------------------------------------------------------------------------
#define CPB 2
__global__ __launch_bounds__(256) void kv_ctx_gemm(const _Float16* __restrict__ Ahp,
                                                   const _Float16* __restrict__ Bt,
                                                   float* __restrict__ pbuf,
                                                   float* __restrict__ rsbuf) {
  union alignas(16) KVU {
    _Float16 st[3][2][128 * 32];  // [buf][A,B] 48 KB 3-deep staging
    _Float16 ev[128][136];        // 34.8 KB epilogue: rows 0..63 exp(k), 64..127 v
  };
  __shared__ KVU u;
  const int tid = threadIdx.x;
  const int cg = blockIdx.x;     // 0..15 chunk-group (2 chunks of 128 each)
  const int hi = blockIdx.y;     // head 0..3
  const int b = blockIdx.z;
  const _Float16* Bp = Bt + (long)b * NPIX * 256;
  const int wv = tid >> 6, l = tid & 63;
  const int r16 = l & 15, q = l >> 4;
  const int mb = (wv >> 1) * 64, nb = (wv & 1) * 64;
  const int r1 = tid >> 2;
  const int o1 = ((tid & 3) * 8) ^ (((r1 >> 1) & 3) * 8);
  const int ldsc1 = (wv * 64) * 8;
  const int ldsc2 = (256 + wv * 64) * 8;
  const int q8 = (q * 8) ^ (((r16 >> 1) & 3) * 8);
  // A rows: local 0..63 = k[head hi], 64..127 = v[head hi]
  const long gAk = (long)(256 + hi * 64 + r1) * 256;
  const long gAv = (long)(512 + hi * 64 + r1) * 256;

  auto STAGE = [&](int buf, int kt, int n0) {
    const int k0 = kt * 32;
    async16(&u.st[buf][0][ldsc1], &Ahp[gAk + k0 + o1]);
    async16(&u.st[buf][0][ldsc2], &Ahp[gAv + k0 + o1]);
    async16(&u.st[buf][1][ldsc1], &Bp[(long)(n0 + r1) * 256 + k0 + o1]);
    async16(&u.st[buf][1][ldsc2], &Bp[(long)(n0 + 64 + r1) * 256 + k0 + o1]);
  };

  floatx4 c2[4];
#pragma unroll
  for (int j = 0; j < 4; j++) c2[j] = (floatx4){0.f, 0.f, 0.f, 0.f};
  float rs = 0.f;

  for (int cs = 0; cs < CPB; cs++) {
    const int n0 = (cg * CPB + cs) * 128;
    floatx4 acc[4][4];
#pragma unroll
    for (int i = 0; i < 4; i++)
#pragma unroll
      for (int j = 0; j < 4; j++) acc[i][j] = (floatx4){0.f, 0.f, 0.f, 0.f};

    STAGE(0, 0, n0);
    STAGE(1, 1, n0);
    pipe_barrier(4);  // stage0 landed (stage1 in flight)
    int cc = 0;
    for (int kt = 0; kt < 8; kt++) {
      if (kt < 6) {
        int sb = cc + 2;
        if (sb >= 3) sb -= 3;
        STAGE(sb, kt + 2, n0);
      }
      half8 fa[4], fb[4];
#pragma unroll
      for (int i = 0; i < 4; i++) {
        fa[i] = *(const half8*)&u.st[cc][0][(mb + i * 16 + r16) * 32 + q8];
        fb[i] = *(const half8*)&u.st[cc][1][(nb + i * 16 + r16) * 32 + q8];
      }
#pragma unroll
      for (int i = 0; i < 4; i++)
#pragma unroll
        for (int j = 0; j < 4; j++)
          acc[i][j] = __builtin_amdgcn_mfma_f32_16x16x32_f16(fa[i], fb[j], acc[i][j], 0, 0, 0);
      pipe_barrier(kt < 6 ? 4 : 0);
      cc = (cc == 2) ? 0 : cc + 1;
    }

    // ---- epilogue: acc -> exp(k)/v fp16 tile in LDS (stride 136) ----
    // (vmcnt=0 drained + fenced barrier -> ev overlay safe)
    const bool is_k = (mb == 0);
#pragma unroll
    for (int i = 0; i < 4; i++) {
      const int row = mb + i * 16 + q * 4;
#pragma unroll
      for (int j = 0; j < 4; j++) {
        const int col = nb + j * 16 + r16;
#pragma unroll
        for (int t = 0; t < 4; t++) {
          const float vv0 = acc[i][j][t];
          u.ev[row + t][col] = (_Float16)(is_k ? __expf(vv0) : vv0);
        }
      }
    }
    __syncthreads();

    // ---- context partial: c2[d][e] += sum_n exp(k[d][n]) v[e][n], K=128 ----
#pragma unroll
    for (int ks = 0; ks < 4; ks++) {
      half8 a = *(const half8*)&u.ev[wv * 16 + r16][ks * 32 + q * 8];
#pragma unroll
      for (int ii = 0; ii < 8; ii++) rs += (float)a[ii];
#pragma unroll
      for (int j = 0; j < 4; j++) {
        half8 bv = *(const half8*)&u.ev[64 + j * 16 + r16][ks * 32 + q * 8];
        c2[j] = __builtin_amdgcn_mfma_f32_16x16x32_f16(a, bv, c2[j], 0, 0, 0);
      }
    }
    __syncthreads();  // ev reads done before next chunk's STAGE overwrites
  }

  rs += __shfl_xor(rs, 16, 64);
  rs += __shfl_xor(rs, 32, 64);
  const int bh = b * 4 + hi;
  float* pp = pbuf + ((long)bh * 16 + cg) * 4096;
#pragma unroll
  for (int j = 0; j < 4; j++)
#pragma unroll
    for (int reg = 0; reg < 4; reg++)
      pp[(wv * 16 + q * 4 + reg) * 64 + j * 16 + r16] = c2[j][reg];
  if (l < 16) rsbuf[((long)bh * 16 + cg) * 64 + wv * 16 + r16] = rs;
}

// ---------------------------------------------------------------------------
// FUSED reduce_ctx + zinv + mctx:
//   ctx[d][e] = sum_16 pbuf partials; kinvz[d] = 1/sum_16 rsbuf
//   M_b[c][h*64+d] = SCALE * kinvz[d] * sum_e w_out[c][h*64+e] * ctx[d][e]
// ---------------------------------------------------------------------------
__global__ __launch_bounds__(256) void mctx_fused(const float* __restrict__ w_out,
                                                  const float* __restrict__ pbuf,
                                                  const float* __restrict__ rsbuf,
                                                  _Float16* __restrict__ Mhi,
                                                  _Float16* __restrict__ Mlo) {
  __shared__ float sctxT[64][65];  // [e][d], +1 pad
  __shared__ float sinv[64];
  const int cq = blockIdx.x, h = blockIdx.y, b = blockIdx.z;
  const int bh = b * 4 + h;
  const float* pp = pbuf + (long)bh * 16 * 4096;  // 16 partials of [d][e]
  const int tid = threadIdx.x;
  {
    const int d = tid >> 2, e0 = (tid & 3) * 16;
    float s0[16];
#pragma unroll
    for (int i = 0; i < 16; i++) s0[i] = 0.f;
    for (int c = 0; c < 16; c++) {
#pragma unroll
      for (int k = 0; k < 4; k++) {
        float4 v = *(const float4*)&pp[(long)c * 4096 + d * 64 + e0 + k * 4];
        s0[k * 4 + 0] += v.x;
        s0[k * 4 + 1] += v.y;
        s0[k * 4 + 2] += v.z;
        s0[k * 4 + 3] += v.w;
      }
    }
#pragma unroll
    for (int i = 0; i < 16; i++) sctxT[e0 + i][d] = s0[i];
  }
  if (tid < 64) {
    const float* rp = rsbuf + (long)bh * 16 * 64 + tid;
    float z = 0.f;
#pragma unroll
    for (int c = 0; c < 16; c++) z += rp[c * 64];
    sinv[tid] = 1.0f / z;
  }
  __syncthreads();
  const int c = cq * 64 + (tid >> 2);
  const int d0 = (tid & 3) * 16;
  const float* wp = w_out + (long)c * 256 + h * 64;
  float acc[16];
#pragma unroll
  for (int i = 0; i < 16; i++) acc[i] = 0.f;
#pragma unroll
  for (int e4 = 0; e4 < 16; e4++) {
    float4 wv = *(const float4*)&wp[e4 * 4];
#pragma unroll
    for (int u2 = 0; u2 < 4; u2++) {
      const float we = ((const float*)&wv)[u2];
      const int e = e4 * 4 + u2;
#pragma unroll
      for (int dd = 0; dd < 16; dd++) acc[dd] = fmaf(we, sctxT[e][d0 + dd], acc[dd]);
    }
  }
  alignas(16) _Float16 hi16[16], lo16[16];
#pragma unroll
  for (int k4 = 0; k4 < 4; k4++) {
    float4 zv = *(const float4*)&sinv[d0 + k4 * 4];
#pragma unroll
    for (int u2 = 0; u2 < 4; u2++) {
      const int dd = k4 * 4 + u2;
      float v = acc[dd] * (SCALE * ((const float*)&zv)[u2]);
      _Float16 hh = (_Float16)v;
      hi16[dd] = hh;
      lo16[dd] = (_Float16)(v - (float)hh);
    }
  }
  _Float16* mh = Mhi + ((long)b * 256 + c) * 256 + h * 64 + d0;
  _Float16* ml = Mlo + ((long)b * 256 + c) * 256 + h * 64 + d0;
#pragma unroll
  for (int k = 0; k < 2; k++) {
    *(float4*)&mh[k * 8] = *(float4*)&hi16[k * 8];
    *(float4*)&ml[k * 8] = *(float4*)&lo16[k * 8];
  }
}

// ---------------------------------------------------------------------------
// final GEMM: out[b][256][4096] = (Mhi+Mlo)[b] @ PT[b]^T + b_out
// B layout: PT[b][s][4096][128], s = K-half (kt>>2). 3-DEEP counted-vmcnt
// pipeline (72 KB LDS, 2 blocks/CU).
// ---------------------------------------------------------------------------
__global__ __launch_bounds__(256) void out_gemm(const _Float16* __restrict__ Mhi,
                                                const _Float16* __restrict__ Mlo,
                                                const _Float16* __restrict__ PT,
                                                float* __restrict__ C,
                                                const float* __restrict__ bias) {
  __shared__ _Float16 st[3][3][128 * 32];  // 72 KB 3-deep staging
  const int tid = threadIdx.x;
  const int n0 = blockIdx.x * 128, m0 = blockIdx.y * 128;
  const int b = blockIdx.z;
  const _Float16* Ah = Mhi + (long)b * 65536;
  const _Float16* Al = Mlo + (long)b * 65536;
  float* Cp = C + (long)b * 256 * NPIX;
  const int wv = tid >> 6, l = tid & 63;
  const int r16 = l & 15, q = l >> 4;
  const int mb = (wv >> 1) * 64, nb = (wv & 1) * 64;
  const int r1 = tid >> 2;
  const int o1 = ((tid & 3) * 8) ^ (((r1 >> 1) & 3) * 8);
  const int r2 = r1 + 64;
  const int ldsc1 = (wv * 64) * 8;
  const int ldsc2 = (256 + wv * 64) * 8;
  const int q8 = (q * 8) ^ (((r16 >> 1) & 3) * 8);

  auto STAGE = [&](int buf, int kt) {
    const int k0 = kt * 32;
    async16(&st[buf][0][ldsc1], &Ah[(long)(m0 + r1) * 256 + k0 + o1]);
    async16(&st[buf][0][ldsc2], &Ah[(long)(m0 + r2) * 256 + k0 + o1]);
    async16(&st[buf][1][ldsc1], &Al[(long)(m0 + r1) * 256 + k0 + o1]);
    async16(&st[buf][1][ldsc2], &Al[(long)(m0 + r2) * 256 + k0 + o1]);
    const _Float16* Bk = PT + ((long)(b * 2 + (kt >> 2)) * NPIX + n0) * 128;
    async16(&st[buf][2][ldsc1], &Bk[(long)r1 * 128 + (kt & 3) * 32 + o1]);
    async16(&st[buf][2][ldsc2], &Bk[(long)(r1 + 64) * 128 + (kt & 3) * 32 + o1]);
  };

  floatx4 acc[4][4];
#pragma unroll
  for (int i = 0; i < 4; i++)
#pragma unroll
    for (int j = 0; j < 4; j++) acc[i][j] = (floatx4){0.f, 0.f, 0.f, 0.f};

  STAGE(0, 0);
  STAGE(1, 1);
  pipe_barrier(6);
  int cc = 0;
  for (int kt = 0; kt < 8; kt++) {
    if (kt < 6) {
      int sb = cc + 2;
      if (sb >= 3) sb -= 3;
      STAGE(sb, kt + 2);
    }
    half8 fa[4], flo[4], fb[4];
#pragma unroll
    for (int i = 0; i < 4; i++) {
      fa[i] = *(const half8*)&st[cc][0][(mb + i * 16 + r16) * 32 + q8];
      flo[i] = *(const half8*)&st[cc][1][(mb + i * 16 + r16) * 32 + q8];
      fb[i] = *(const half8*)&st[cc][2][(nb + i * 16 + r16) * 32 + q8];
    }
#pragma unroll
    for (int i = 0; i < 4; i++)
#pragma unroll
      for (int j = 0; j < 4; j++) {
        acc[i][j] = __builtin_amdgcn_mfma_f32_16x16x32_f16(fa[i], fb[j], acc[i][j], 0, 0, 0);
        acc[i][j] = __builtin_amdgcn_mfma_f32_16x16x32_f16(flo[i], fb[j], acc[i][j], 0, 0, 0);
      }
    pipe_barrier(kt < 6 ? 6 : 0);
    cc = (cc == 2) ? 0 : cc + 1;
  }
#pragma unroll
  for (int i = 0; i < 4; i++) {
    const int mrow = m0 + mb + i * 16 + q * 4;
#pragma unroll
    for (int t = 0; t < 4; t++) {
      float bz = bias[mrow + t];
#pragma unroll
      for (int j = 0; j < 4; j++) {
        Cp[(long)(mrow + t) * NPIX + n0 + nb + j * 16 + r16] = acc[i][j][t] + bz;
      }
    }
  }
}

extern "C" void kernel_launch(void* const* d_in, const int* in_sizes, int n_in,
                              void* d_out, int out_size, void* d_ws, size_t ws_size,
                              hipStream_t stream) {
  const float* x = (const float*)d_in[0];      // [16][256][4096]
  const float* w_qkv = (const float*)d_in[1];  // [768][256]
  const float* w_out = (const float*)d_in[2];  // [256][256]
  const float* b_out = (const float*)d_in[3];  // [256]
  float* out = (float*)d_out;                  // [16][256][4096]

  // d_ws layout:
  _Float16* PT = (_Float16*)d_ws;                           // [16][2][4096][128] = 32 MB
  float* rsbuf = (float*)(PT + (long)16 * 2 * NPIX * 128);  // 64bh*16p*64 = 256 KB
  _Float16* wq_hi = (_Float16*)(rsbuf + 64 * 16 * 64);
  _Float16* wq_lo = wq_hi + 768 * 256;
  _Float16* Mhi = wq_lo + 768 * 256;                        // 16*256*256 fp16 = 2 MB
  _Float16* Mlo = Mhi + 16 * 256 * 256;                     // 2 MB
  // d_out scratch (dead until out_gemm writes it):
  _Float16* xt = (_Float16*)d_out;                          // [0..32MB)
  float* pbuf = (float*)d_out + (1 << 23);                  // [32MB..48MB): 64bh*16p*4096

  split16_kernel<<<768, 256, 0, stream>>>(w_qkv, wq_hi, wq_lo, 768 * 256);
  transpose16_kernel<<<dim3(64, 4, 16), 256, 0, stream>>>(x, xt);
  // fused k/v GEMM (single-fp16 A) + exp(k)@v^T context partials
  kv_ctx_gemm<<<dim3(16, 4, 16), 256, 0, stream>>>(wq_hi, xt, pbuf, rsbuf);
  // fused partial-reduce + 1/Z + M_b = w_out @ ctx^T * diag(SCALE*invZ)
  mctx_fused<<<dim3(4, 4, 16), 256, 0, stream>>>(w_out, pbuf, rsbuf, Mhi, Mlo);
  // fused q GEMM + softmax -> P fp16 (q fp32 never touches HBM)
  q_gemm_softmax<<<dim3(32, 2, 16), 256, 0, stream>>>(wq_hi, wq_lo, xt, PT);
  // final = M_b @ P_b + b_out
  out_gemm<<<dim3(32, 2, 16), 256, 0, stream>>>(Mhi, Mlo, PT, out, b_out);
}

// Round 10
// 200.816 us; speedup vs baseline: 1.0604x; 1.0438x over previous
//
#include <hip/hip_runtime.h>

#define NPIX 4096
#define SCALE 0.125f

typedef _Float16 half8 __attribute__((ext_vector_type(8)));
typedef _Float16 half4 __attribute__((ext_vector_type(4)));
typedef float floatx4 __attribute__((ext_vector_type(4)));

// async global->LDS, 16B per lane. lds base must be wave-uniform; data lands
// at base + lane*16 (gfx950 semantics, learn_hip m97/m104).
__device__ __forceinline__ void async16(void* lds, const void* g) {
  __builtin_amdgcn_global_load_lds(
      (const __attribute__((address_space(1))) unsigned int*)(uintptr_t)g,
      (__attribute__((address_space(3))) unsigned int*)(unsigned)(uintptr_t)lds,
      16, 0, 0);
}

// counted vmem wait (T4): n is wave-uniform; literal immediates per branch.
__device__ __forceinline__ void vmwait(int n) {
  if (n >= 6)      asm volatile("s_waitcnt vmcnt(6)" ::: "memory");
  else if (n >= 4) asm volatile("s_waitcnt vmcnt(4)" ::: "memory");
  else             asm volatile("s_waitcnt vmcnt(0)" ::: "memory");
}

// raw s_barrier is NOT a compiler memory fence (round-8 race, rule #18):
// sched_barrier(0) on both sides pins the scheduling region boundary.
__device__ __forceinline__ void pipe_barrier(int n) {
  __builtin_amdgcn_sched_barrier(0);
  vmwait(n);
  __builtin_amdgcn_s_barrier();
  __builtin_amdgcn_sched_barrier(0);
}

// ---------------------------------------------------------------------------
// split fp32 -> hi/lo fp16 (a = hi + lo, ~21 mantissa bits kept)
// ---------------------------------------------------------------------------
__global__ __launch_bounds__(256) void split16_kernel(const float* __restrict__ w,
                                                      _Float16* __restrict__ hi,
                                                      _Float16* __restrict__ lo, int n) {
  int i = blockIdx.x * 256 + threadIdx.x;
  if (i < n) {
    float v = w[i];
    _Float16 h = (_Float16)v;
    hi[i] = h;
    lo[i] = (_Float16)(v - (float)h);
  }
}

// ---------------------------------------------------------------------------
// x[b][256][4096] fp32 -> xt[b][4096][256] fp16 (K-contiguous for B-operand)
// ---------------------------------------------------------------------------
__global__ __launch_bounds__(256) void transpose16_kernel(const float* __restrict__ x,
                                                          _Float16* __restrict__ xt) {
  __shared__ float t[64][65];
  const int n0 = blockIdx.x * 64, c0 = blockIdx.y * 64, b = blockIdx.z;
  const float* xp = x + (long)b * 256 * NPIX;
  const int tid = threadIdx.x;
  const int r = tid >> 4, c4 = (tid & 15) * 4;
#pragma unroll
  for (int p = 0; p < 4; p++) {
    float4 v = *(const float4*)&xp[(long)(c0 + r + p * 16) * NPIX + n0 + c4];
    t[r + p * 16][c4 + 0] = v.x;
    t[r + p * 16][c4 + 1] = v.y;
    t[r + p * 16][c4 + 2] = v.z;
    t[r + p * 16][c4 + 3] = v.w;
  }
  __syncthreads();
  const int n = tid >> 2, cg = (tid & 3) * 16;
  alignas(16) _Float16 o[16];
#pragma unroll
  for (int i = 0; i < 16; i++) o[i] = (_Float16)t[cg + i][n];
  _Float16* dst = &xt[((long)b * NPIX + n0 + n) * 256 + c0 + cg];
  *(float4*)dst = *(float4*)&o[0];
  *(float4*)(dst + 8) = *(float4*)&o[8];
}

// ---------------------------------------------------------------------------
// FUSED k/v GEMM (single-fp16 A) + exp(k)@v^T context partials. 3-DEEP
// counted-vmcnt pipeline; 3x16KB staging = 48 KB union (3 blocks/CU).
// Byte-identical to round 9 (passed, absmax 6.1e-5).
// ---------------------------------------------------------------------------
#define CPB 2
__global__ __launch_bounds__(256) void kv_ctx_gemm(const _Float16* __restrict__ Ahp,
                                                   const _Float16* __restrict__ Bt,
                                                   float* __restrict__ pbuf,
                                                   float* __restrict__ rsbuf) {
  union alignas(16) KVU {
    _Float16 st[3][2][128 * 32];  // [buf][A,B] 48 KB 3-deep staging
    _Float16 ev[128][136];        // 34.8 KB epilogue: rows 0..63 exp(k), 64..127 v
  };
  __shared__ KVU u;
  const int tid = threadIdx.x;
  const int cg = blockIdx.x;     // 0..15 chunk-group (2 chunks of 128 each)
  const int hi = blockIdx.y;     // head 0..3
  const int b = blockIdx.z;
  const _Float16* Bp = Bt + (long)b * NPIX * 256;
  const int wv = tid >> 6, l = tid & 63;
  const int r16 = l & 15, q = l >> 4;
  const int mb = (wv >> 1) * 64, nb = (wv & 1) * 64;
  const int r1 = tid >> 2;
  const int o1 = ((tid & 3) * 8) ^ (((r1 >> 1) & 3) * 8);
  const int ldsc1 = (wv * 64) * 8;
  const int ldsc2 = (256 + wv * 64) * 8;
  const int q8 = (q * 8) ^ (((r16 >> 1) & 3) * 8);
  const long gAk = (long)(256 + hi * 64 + r1) * 256;
  const long gAv = (long)(512 + hi * 64 + r1) * 256;

  auto STAGE = [&](int buf, int kt, int n0) {
    const int k0 = kt * 32;
    async16(&u.st[buf][0][ldsc1], &Ahp[gAk + k0 + o1]);
    async16(&u.st[buf][0][ldsc2], &Ahp[gAv + k0 + o1]);
    async16(&u.st[buf][1][ldsc1], &Bp[(long)(n0 + r1) * 256 + k0 + o1]);
    async16(&u.st[buf][1][ldsc2], &Bp[(long)(n0 + 64 + r1) * 256 + k0 + o1]);
  };

  floatx4 c2[4];
#pragma unroll
  for (int j = 0; j < 4; j++) c2[j] = (floatx4){0.f, 0.f, 0.f, 0.f};
  float rs = 0.f;

  for (int cs = 0; cs < CPB; cs++) {
    const int n0 = (cg * CPB + cs) * 128;
    floatx4 acc[4][4];
#pragma unroll
    for (int i = 0; i < 4; i++)
#pragma unroll
      for (int j = 0; j < 4; j++) acc[i][j] = (floatx4){0.f, 0.f, 0.f, 0.f};

    STAGE(0, 0, n0);
    STAGE(1, 1, n0);
    pipe_barrier(4);  // stage0 landed (stage1 in flight)
    int cc = 0;
    for (int kt = 0; kt < 8; kt++) {
      if (kt < 6) {
        int sb = cc + 2;
        if (sb >= 3) sb -= 3;
        STAGE(sb, kt + 2, n0);
      }
      half8 fa[4], fb[4];
#pragma unroll
      for (int i = 0; i < 4; i++) {
        fa[i] = *(const half8*)&u.st[cc][0][(mb + i * 16 + r16) * 32 + q8];
        fb[i] = *(const half8*)&u.st[cc][1][(nb + i * 16 + r16) * 32 + q8];
      }
#pragma unroll
      for (int i = 0; i < 4; i++)
#pragma unroll
        for (int j = 0; j < 4; j++)
          acc[i][j] = __builtin_amdgcn_mfma_f32_16x16x32_f16(fa[i], fb[j], acc[i][j], 0, 0, 0);
      pipe_barrier(kt < 6 ? 4 : 0);
      cc = (cc == 2) ? 0 : cc + 1;
    }

    const bool is_k = (mb == 0);
#pragma unroll
    for (int i = 0; i < 4; i++) {
      const int row = mb + i * 16 + q * 4;
#pragma unroll
      for (int j = 0; j < 4; j++) {
        const int col = nb + j * 16 + r16;
#pragma unroll
        for (int t = 0; t < 4; t++) {
          const float vv0 = acc[i][j][t];
          u.ev[row + t][col] = (_Float16)(is_k ? __expf(vv0) : vv0);
        }
      }
    }
    __syncthreads();

#pragma unroll
    for (int ks = 0; ks < 4; ks++) {
      half8 a = *(const half8*)&u.ev[wv * 16 + r16][ks * 32 + q * 8];
#pragma unroll
      for (int ii = 0; ii < 8; ii++) rs += (float)a[ii];
#pragma unroll
      for (int j = 0; j < 4; j++) {
        half8 bv = *(const half8*)&u.ev[64 + j * 16 + r16][ks * 32 + q * 8];
        c2[j] = __builtin_amdgcn_mfma_f32_16x16x32_f16(a, bv, c2[j], 0, 0, 0);
      }
    }
    __syncthreads();  // ev reads done before next chunk's STAGE overwrites
  }

  rs += __shfl_xor(rs, 16, 64);
  rs += __shfl_xor(rs, 32, 64);
  const int bh = b * 4 + hi;
  float* pp = pbuf + ((long)bh * 16 + cg) * 4096;
#pragma unroll
  for (int j = 0; j < 4; j++)
#pragma unroll
    for (int reg = 0; reg < 4; reg++)
      pp[(wv * 16 + q * 4 + reg) * 64 + j * 16 + r16] = c2[j][reg];
  if (l < 16) rsbuf[((long)bh * 16 + cg) * 64 + wv * 16 + r16] = rs;
}

// ---------------------------------------------------------------------------
// FUSED reduce_ctx + zinv + mctx (unchanged from round 9):
//   M_b[c][h*64+d] = SCALE * kinvz[d] * sum_e w_out[c][h*64+e] * ctx[d][e]
// ---------------------------------------------------------------------------
__global__ __launch_bounds__(256) void mctx_fused(const float* __restrict__ w_out,
                                                  const float* __restrict__ pbuf,
                                                  const float* __restrict__ rsbuf,
                                                  _Float16* __restrict__ Mhi,
                                                  _Float16* __restrict__ Mlo) {
  __shared__ float sctxT[64][65];  // [e][d], +1 pad
  __shared__ float sinv[64];
  const int cq = blockIdx.x, h = blockIdx.y, b = blockIdx.z;
  const int bh = b * 4 + h;
  const float* pp = pbuf + (long)bh * 16 * 4096;
  const int tid = threadIdx.x;
  {
    const int d = tid >> 2, e0 = (tid & 3) * 16;
    float s0[16];
#pragma unroll
    for (int i = 0; i < 16; i++) s0[i] = 0.f;
    for (int c = 0; c < 16; c++) {
#pragma unroll
      for (int k = 0; k < 4; k++) {
        float4 v = *(const float4*)&pp[(long)c * 4096 + d * 64 + e0 + k * 4];
        s0[k * 4 + 0] += v.x;
        s0[k * 4 + 1] += v.y;
        s0[k * 4 + 2] += v.z;
        s0[k * 4 + 3] += v.w;
      }
    }
#pragma unroll
    for (int i = 0; i < 16; i++) sctxT[e0 + i][d] = s0[i];
  }
  if (tid < 64) {
    const float* rp = rsbuf + (long)bh * 16 * 64 + tid;
    float z = 0.f;
#pragma unroll
    for (int c = 0; c < 16; c++) z += rp[c * 64];
    sinv[tid] = 1.0f / z;
  }
  __syncthreads();
  const int c = cq * 64 + (tid >> 2);
  const int d0 = (tid & 3) * 16;
  const float* wp = w_out + (long)c * 256 + h * 64;
  float acc[16];
#pragma unroll
  for (int i = 0; i < 16; i++) acc[i] = 0.f;
#pragma unroll
  for (int e4 = 0; e4 < 16; e4++) {
    float4 wv = *(const float4*)&wp[e4 * 4];
#pragma unroll
    for (int u2 = 0; u2 < 4; u2++) {
      const float we = ((const float*)&wv)[u2];
      const int e = e4 * 4 + u2;
#pragma unroll
      for (int dd = 0; dd < 16; dd++) acc[dd] = fmaf(we, sctxT[e][d0 + dd], acc[dd]);
    }
  }
  alignas(16) _Float16 hi16[16], lo16[16];
#pragma unroll
  for (int k4 = 0; k4 < 4; k4++) {
    float4 zv = *(const float4*)&sinv[d0 + k4 * 4];
#pragma unroll
    for (int u2 = 0; u2 < 4; u2++) {
      const int dd = k4 * 4 + u2;
      float v = acc[dd] * (SCALE * ((const float*)&zv)[u2]);
      _Float16 hh = (_Float16)v;
      hi16[dd] = hh;
      lo16[dd] = (_Float16)(v - (float)hh);
    }
  }
  _Float16* mh = Mhi + ((long)b * 256 + c) * 256 + h * 64 + d0;
  _Float16* ml = Mlo + ((long)b * 256 + c) * 256 + h * 64 + d0;
#pragma unroll
  for (int k = 0; k < 2; k++) {
    *(float4*)&mh[k * 8] = *(float4*)&hi16[k * 8];
    *(float4*)&ml[k * 8] = *(float4*)&lo16[k * 8];
  }
}

// ---------------------------------------------------------------------------
// FUSED q-GEMM + softmax + out-GEMM: one 512-thread block computes the FULL
// 256-c P column block for its 128-n tile (split-A q GEMM + per-column
// softmax -> P in LDS), then out[:, n-tile] = (Mhi+Mlo) @ P + bias directly.
// PT never touches HBM; out_gemm dispatch eliminated. M staging for phase 2
// is issued BEFORE the softmax (latency hides under it, T14).
// LDS: 2x40KB staging + 64KB P = 144 KB -> 1 block/CU (8 waves, 2/SIMD).
// ---------------------------------------------------------------------------
__global__ __launch_bounds__(512) void qout_fused(const _Float16* __restrict__ wqh,
                                                  const _Float16* __restrict__ wql,
                                                  const _Float16* __restrict__ xt,
                                                  const _Float16* __restrict__ Mhi,
                                                  const _Float16* __restrict__ Mlo,
                                                  const float* __restrict__ bias,
                                                  float* __restrict__ out) {
  struct alignas(16) QO {
    _Float16 st[2][20480];  // [buf]: Ah[0,8K) Al[8K,16K) B[16K,20K) elems (40 KB)
    _Float16 P[128][256];   // softmax(q): [n][c], c XOR-swizzled (64 KB)
  };
  __shared__ QO u;
  const int tid = threadIdx.x;
  const int n0 = blockIdx.x * 128;
  const int b = blockIdx.y;
  const _Float16* Bp = xt + (long)b * NPIX * 256;
  const _Float16* MhB = Mhi + (long)b * 65536;
  const _Float16* MlB = Mlo + (long)b * 65536;
  float* Cp = out + (long)b * 256 * NPIX;
  const int wv = tid >> 6, l = tid & 63;
  const int r16 = l & 15, q = l >> 4;
  const int mb = (wv >> 1) * 64;  // 4 m-waves x 64 (covers 256 rows)
  const int nb = (wv & 1) * 64;   // 2 n-waves x 64 (covers 128 cols)
  const int r1 = tid >> 2;        // 0..127
  const int o1 = ((tid & 3) * 8) ^ (((r1 >> 1) & 3) * 8);  // key same for r1 and r1+128
  const int ldsW = wv * 512;      // wave's 1KB slice per async16 call
  const int q8 = (q * 8) ^ (((r16 >> 1) & 3) * 8);

  // phase-1 staging: q weights rows 0..255 (hi+lo) + xt n-rows (8KB/call x5)
  auto STAGE1 = [&](int buf, int kt) {
    const int k0 = kt * 32;
    async16(&u.st[buf][0 + ldsW], &wqh[(long)r1 * 256 + k0 + o1]);
    async16(&u.st[buf][4096 + ldsW], &wqh[(long)(128 + r1) * 256 + k0 + o1]);
    async16(&u.st[buf][8192 + ldsW], &wql[(long)r1 * 256 + k0 + o1]);
    async16(&u.st[buf][12288 + ldsW], &wql[(long)(128 + r1) * 256 + k0 + o1]);
    async16(&u.st[buf][16384 + ldsW], &Bp[(long)(n0 + r1) * 256 + k0 + o1]);
  };
  // phase-2 staging: M rows 0..255 (hi+lo), K = c
  auto STAGE2 = [&](int buf, int kt) {
    const int k0 = kt * 32;
    async16(&u.st[buf][0 + ldsW], &MhB[(long)r1 * 256 + k0 + o1]);
    async16(&u.st[buf][4096 + ldsW], &MhB[(long)(128 + r1) * 256 + k0 + o1]);
    async16(&u.st[buf][8192 + ldsW], &MlB[(long)r1 * 256 + k0 + o1]);
    async16(&u.st[buf][12288 + ldsW], &MlB[(long)(128 + r1) * 256 + k0 + o1]);
  };

  // ---- phase 1: q = (Wq_hi+Wq_lo) @ xt^T, 256 c x 128 n ----
  floatx4 acc[4][4];
#pragma unroll
  for (int i = 0; i < 4; i++)
#pragma unroll
    for (int j = 0; j < 4; j++) acc[i][j] = (floatx4){0.f, 0.f, 0.f, 0.f};

  STAGE1(0, 0);
  __syncthreads();
  for (int kt = 0; kt < 8; kt++) {
    const int cur = kt & 1;
    if (kt < 7) STAGE1(cur ^ 1, kt + 1);
    half8 fa[4], flo[4], fb[4];
#pragma unroll
    for (int i = 0; i < 4; i++) {
      fa[i] = *(const half8*)&u.st[cur][(mb + i * 16 + r16) * 32 + q8];
      flo[i] = *(const half8*)&u.st[cur][8192 + (mb + i * 16 + r16) * 32 + q8];
      fb[i] = *(const half8*)&u.st[cur][16384 + (nb + i * 16 + r16) * 32 + q8];
    }
#pragma unroll
    for (int i = 0; i < 4; i++)
#pragma unroll
      for (int j = 0; j < 4; j++) {
        acc[i][j] = __builtin_amdgcn_mfma_f32_16x16x32_f16(fa[i], fb[j], acc[i][j], 0, 0, 0);
        acc[i][j] = __builtin_amdgcn_mfma_f32_16x16x32_f16(flo[i], fb[j], acc[i][j], 0, 0, 0);
      }
    __syncthreads();
  }

  // issue M prologue now: latency hides under the softmax (st safe: all waves
  // are past their last fragment reads after the kt=7 barrier)
  STAGE2(0, 0);

  // ---- softmax over d (each wave's 64 m-rows = one head) -> P in LDS ----
#pragma unroll
  for (int j = 0; j < 4; j++) {
    float s = 0.f;
#pragma unroll
    for (int i = 0; i < 4; i++)
#pragma unroll
      for (int t = 0; t < 4; t++) {
        float e = __expf(acc[i][j][t]);
        acc[i][j][t] = e;
        s += e;
      }
    s += __shfl_xor(s, 16, 64);
    s += __shfl_xor(s, 32, 64);
    const float rinv = 1.0f / s;
    const int nl = nb + j * 16 + r16;   // 0..127
    const int swz = (nl & 7) * 8;       // XOR on c-bits 3..5 (bijective per half4)
#pragma unroll
    for (int i = 0; i < 4; i++) {
      half4 h4;
#pragma unroll
      for (int t = 0; t < 4; t++) h4[t] = (_Float16)(acc[i][j][t] * rinv);
      *(half4*)&u.P[nl][(mb + i * 16 + q * 4) ^ swz] = h4;
    }
  }
  __syncthreads();  // drains vmcnt (M buf0 landed) + P visible to all waves

  // ---- phase 2: out = (Mhi+Mlo) @ P + bias, 256 rows x 128 n, K = 256 c ----
  floatx4 ac2[4][4];
#pragma unroll
  for (int i = 0; i < 4; i++)
#pragma unroll
    for (int j = 0; j < 4; j++) ac2[i][j] = (floatx4){0.f, 0.f, 0.f, 0.f};

  for (int kt = 0; kt < 8; kt++) {
    const int cur = kt & 1;
    if (kt < 7) STAGE2(cur ^ 1, kt + 1);
    half8 fa[4], flo[4], fb[4];
#pragma unroll
    for (int i = 0; i < 4; i++) {
      fa[i] = *(const half8*)&u.st[cur][(mb + i * 16 + r16) * 32 + q8];
      flo[i] = *(const half8*)&u.st[cur][8192 + (mb + i * 16 + r16) * 32 + q8];
      const int nrow = nb + i * 16 + r16;
      fb[i] = *(const half8*)&u.P[nrow][(kt * 32 + q * 8) ^ ((nrow & 7) * 8)];
    }
#pragma unroll
    for (int i = 0; i < 4; i++)
#pragma unroll
      for (int j = 0; j < 4; j++) {
        ac2[i][j] = __builtin_amdgcn_mfma_f32_16x16x32_f16(fa[i], fb[j], ac2[i][j], 0, 0, 0);
        ac2[i][j] = __builtin_amdgcn_mfma_f32_16x16x32_f16(flo[i], fb[j], ac2[i][j], 0, 0, 0);
      }
    __syncthreads();
  }

#pragma unroll
  for (int i = 0; i < 4; i++) {
    const int mrow = mb + i * 16 + q * 4;
#pragma unroll
    for (int t = 0; t < 4; t++) {
      float bz = bias[mrow + t];
#pragma unroll
      for (int j = 0; j < 4; j++) {
        Cp[(long)(mrow + t) * NPIX + n0 + nb + j * 16 + r16] = ac2[i][j][t] + bz;
      }
    }
  }
}

extern "C" void kernel_launch(void* const* d_in, const int* in_sizes, int n_in,
                              void* d_out, int out_size, void* d_ws, size_t ws_size,
                              hipStream_t stream) {
  const float* x = (const float*)d_in[0];      // [16][256][4096]
  const float* w_qkv = (const float*)d_in[1];  // [768][256]
  const float* w_out = (const float*)d_in[2];  // [256][256]
  const float* b_out = (const float*)d_in[3];  // [256]
  float* out = (float*)d_out;                  // [16][256][4096]

  // d_ws layout (out is written by qout_fused, so NO scratch lives in d_out):
  _Float16* xt = (_Float16*)d_ws;                           // [16][4096][256] f16 = 33.5 MB
  float* pbuf = (float*)(xt + (long)16 * NPIX * 256);       // 64bh*16p*4096 f32 = 16.8 MB
  float* rsbuf = pbuf + (long)64 * 16 * 4096;               // 256 KB
  _Float16* wq_hi = (_Float16*)(rsbuf + 64 * 16 * 64);
  _Float16* wq_lo = wq_hi + 768 * 256;
  _Float16* Mhi = wq_lo + 768 * 256;                        // 2 MB
  _Float16* Mlo = Mhi + 16 * 256 * 256;                     // 2 MB

  split16_kernel<<<768, 256, 0, stream>>>(w_qkv, wq_hi, wq_lo, 768 * 256);
  transpose16_kernel<<<dim3(64, 4, 16), 256, 0, stream>>>(x, xt);
  // fused k/v GEMM (single-fp16 A) + exp(k)@v^T context partials
  kv_ctx_gemm<<<dim3(16, 4, 16), 256, 0, stream>>>(wq_hi, xt, pbuf, rsbuf);
  // fused partial-reduce + 1/Z + M_b = w_out @ ctx^T * diag(SCALE*invZ)
  mctx_fused<<<dim3(4, 4, 16), 256, 0, stream>>>(w_out, pbuf, rsbuf, Mhi, Mlo);
  // fused q GEMM + softmax + out GEMM (P never touches HBM)
  qout_fused<<<dim3(32, 16), 512, 0, stream>>>(wq_hi, wq_lo, xt, Mhi, Mlo, b_out, out);
}